// Round 1
// baseline (78.128 us; speedup 1.0000x reference)
//
#include <hip/hip_runtime.h>
#include <hip/hip_bf16.h>

typedef __bf16 bf16x8 __attribute__((ext_vector_type(8)));
typedef float f32x4 __attribute__((ext_vector_type(4)));

#define BN_EPS 1e-5f

// One wave (64 lanes) processes one output row m per loop iteration.
//   A-frag (per k-tile kt): lane l holds G[kt*16 + (l&15)][8*(l>>4) + j], j=0..7
//                          = 8 contiguous channels of one gathered neighbor.
//   B-frag (per o-tile t):  lane l holds W[t*16 + (l&15)][8*(l>>4) + j]
//   D:                      lane l, reg r = proj[kt*16 + (l>>4)*4 + r][t*16 + (l&15)]
// BN+bias folded to y = d*S[o] + T[o]; ReLU folds into max (acc starts at 0).
__global__ __launch_bounds__(256, 4) void down_kernel(
    const float* __restrict__ vf,     // [N,32] voxel features
    const int*   __restrict__ kidx,   // [M,32]
    const int*   __restrict__ kmask,  // [M,32]  (1 = invalid)
    const float* __restrict__ W,      // [64,32]
    const float* __restrict__ bias,   // [64]
    const float* __restrict__ gamma,  // [64]
    const float* __restrict__ beta,   // [64]
    const float* __restrict__ mean,   // [64]
    const float* __restrict__ var,    // [64]
    float* __restrict__ out,          // [M,64]
    int M)
{
    const int lane = threadIdx.x & 63;
    const int col  = lane & 15;       // m/n index within 16x16 tile
    const int grp  = lane >> 4;       // 0..3
    const int c0   = grp << 3;        // channel offset for A/B frags

    const int waves_per_block = blockDim.x >> 6;
    const int wave_id     = blockIdx.x * waves_per_block + (threadIdx.x >> 6);
    const int total_waves = gridDim.x * waves_per_block;

    // ---- loop-invariant: B fragments (W) + BN affine params per o-tile ----
    bf16x8 bfrag[4];
    float S[4], T[4];
#pragma unroll
    for (int t = 0; t < 4; ++t) {
        const int o = t * 16 + col;
        const f32x4 w0 = *(const f32x4*)(W + o * 32 + c0);
        const f32x4 w1 = *(const f32x4*)(W + o * 32 + c0 + 4);
        bf16x8 f;
        f[0] = (__bf16)w0.x; f[1] = (__bf16)w0.y;
        f[2] = (__bf16)w0.z; f[3] = (__bf16)w0.w;
        f[4] = (__bf16)w1.x; f[5] = (__bf16)w1.y;
        f[6] = (__bf16)w1.z; f[7] = (__bf16)w1.w;
        bfrag[t] = f;
        const float s = gamma[o] * rsqrtf(var[o] + BN_EPS);
        S[t] = s;
        T[t] = (bias[o] - mean[o]) * s + beta[o];
    }

    const f32x4 zero4 = {0.f, 0.f, 0.f, 0.f};

    for (int m = wave_id; m < M; m += total_waves) {
        const int* idxp = kidx  + m * 32;
        const int* mskp = kmask + m * 32;

        // ---- gather directly into A fragments (2 k-tiles) ----
        bf16x8 afrag[2];
#pragma unroll
        for (int kt = 0; kt < 2; ++kt) {
            const int k   = kt * 16 + col;
            int       id  = idxp[k];
            const int msk = mskp[k];
            id = id < 0 ? 0 : id;
            const float sel = (msk == 0) ? 1.0f : 0.0f;
            const float* src = vf + (size_t)id * 32 + c0;
            const f32x4 g0 = *(const f32x4*)(src);
            const f32x4 g1 = *(const f32x4*)(src + 4);
            bf16x8 a;
            a[0] = (__bf16)(g0.x * sel); a[1] = (__bf16)(g0.y * sel);
            a[2] = (__bf16)(g0.z * sel); a[3] = (__bf16)(g0.w * sel);
            a[4] = (__bf16)(g1.x * sel); a[5] = (__bf16)(g1.y * sel);
            a[6] = (__bf16)(g1.z * sel); a[7] = (__bf16)(g1.w * sel);
            afrag[kt] = a;
        }

        // ---- 8 MFMAs + fused BN/ReLU/max epilogue ----
        float myout = 0.0f;
#pragma unroll
        for (int t = 0; t < 4; ++t) {
            f32x4 d0 = __builtin_amdgcn_mfma_f32_16x16x32_bf16(afrag[0], bfrag[t], zero4, 0, 0, 0);
            f32x4 d1 = __builtin_amdgcn_mfma_f32_16x16x32_bf16(afrag[1], bfrag[t], zero4, 0, 0, 0);
            float v = 0.0f;                       // ReLU folded in (all candidates >= 0)
#pragma unroll
            for (int r = 0; r < 4; ++r) {
                v = fmaxf(v, d0[r] * S[t] + T[t]);
                v = fmaxf(v, d1[r] * S[t] + T[t]);
            }
            // reduce across the 4 lane-groups (lanes c, c+16, c+32, c+48)
            v = fmaxf(v, __shfl_xor(v, 16));
            v = fmaxf(v, __shfl_xor(v, 32));
            if (grp == t) myout = v;              // lane l owns output channel l
        }
        out[(size_t)m * 64 + lane] = myout;
    }
}

extern "C" void kernel_launch(void* const* d_in, const int* in_sizes, int n_in,
                              void* d_out, int out_size, void* d_ws, size_t ws_size,
                              hipStream_t stream) {
    const float* vf    = (const float*)d_in[0];
    const int*   kidx  = (const int*)  d_in[1];
    const int*   kmask = (const int*)  d_in[2];
    const float* W     = (const float*)d_in[3];
    const float* bias  = (const float*)d_in[4];
    const float* gamma = (const float*)d_in[5];
    const float* beta  = (const float*)d_in[6];
    const float* mean  = (const float*)d_in[7];
    const float* var   = (const float*)d_in[8];
    float* out = (float*)d_out;

    const int M = in_sizes[1] / 32;   // key_indices is [M,32]

    // 2048 blocks x 4 waves = 8192 waves = full 32-wave/CU occupancy target;
    // each wave grid-strides over ~12 rows.
    down_kernel<<<2048, 256, 0, stream>>>(vf, kidx, kmask, W, bias, gamma,
                                          beta, mean, var, out, M);
}